// Round 1
// baseline (787.068 us; speedup 1.0000x reference)
//
#include <hip/hip_runtime.h>
#include <math.h>

// Problem constants
constexpr int Hdim  = 128;
constexpr int Npn   = 64;
constexpr int Eg    = 2016;          // N*(N-1)/2
constexpr int Gg    = 512;
constexpr int TOT   = Gg * Eg;       // 1,032,192 edges (divisible by 256)
constexpr int PITCH = 136;           // LDS row pitch in bf16 elems (16B-aligned rows)

typedef unsigned short ushortx8 __attribute__((ext_vector_type(8)));
typedef __bf16         bf16x8   __attribute__((ext_vector_type(8)));
typedef float          floatx4  __attribute__((ext_vector_type(4)));

static __device__ __forceinline__ unsigned short f2bf(float f) {
    unsigned int u = __float_as_uint(f);
    u += 0x7FFFu + ((u >> 16) & 1u);   // round-to-nearest-even
    return (unsigned short)(u >> 16);
}

static __device__ __forceinline__ float gelu_exact(float x) {
    return 0.5f * x * (1.0f + erff(x * 0.70710678118654752440f));
}

static __device__ __forceinline__ floatx4 mfma16(ushortx8 a, ushortx8 b, floatx4 c) {
    return __builtin_amdgcn_mfma_f32_16x16x32_bf16(
        __builtin_bit_cast(bf16x8, a), __builtin_bit_cast(bf16x8, b), c, 0, 0, 0);
}

// Kernel 1: per-edge MLP scores, scattered to out[g*Eg + idx].
// 256 threads = 4 waves; each block processes 4 tiles of 64 rows (256 rows).
__global__ __launch_bounds__(256, 3)
void scores_kernel(const float* __restrict__ X, const int* __restrict__ ei,
                   const float* __restrict__ lng, const float* __restrict__ lnb,
                   const float* __restrict__ W1, const float* __restrict__ b1,
                   const float* __restrict__ W2, const float* __restrict__ b2,
                   const float* __restrict__ W3, const float* __restrict__ b3,
                   float* __restrict__ out)
{
    __shared__ unsigned short Xl[64 * PITCH];   // LN'd activations, bf16
    __shared__ unsigned short H1l[64 * PITCH];  // gelu(X@W1+b1), bf16
    __shared__ float part[4 * 64];              // per-wave partial dots

    const int tid  = threadIdx.x;
    const int wave = tid >> 6;
    const int lane = tid & 63;
    const int q    = lane >> 4;    // k-group / row-quad
    const int c16  = lane & 15;    // n / m within MFMA tile

    // ---- Weight fragments in registers (loaded once per block) ----
    // GEMM1: wave owns output cols [32*wave, 32*wave+32) -> 2 ctiles x 4 ktiles
    ushortx8 B1f[2][4];
#pragma unroll
    for (int c = 0; c < 2; ++c) {
        const int n = (2 * wave + c) * 16 + c16;
#pragma unroll
        for (int kt = 0; kt < 4; ++kt) {
            ushortx8 f;
#pragma unroll
            for (int j = 0; j < 8; ++j)
                f[j] = f2bf(W1[(kt * 32 + q * 8 + j) * Hdim + n]);
            B1f[c][kt] = f;
        }
    }
    // GEMM2: wave owns output cols [16*wave, 16*wave+16) -> 1 ctile x 4 ktiles
    const int n2 = wave * 16 + c16;
    ushortx8 B2f[4];
#pragma unroll
    for (int kt = 0; kt < 4; ++kt) {
        ushortx8 f;
#pragma unroll
        for (int j = 0; j < 8; ++j)
            f[j] = f2bf(W2[(kt * 32 + q * 8 + j) * 64 + n2]);
        B2f[kt] = f;
    }

    const float b1v0 = b1[(2 * wave) * 16 + c16];
    const float b1v1 = b1[(2 * wave + 1) * 16 + c16];
    const float b2v  = b2[n2];
    const float w3v  = W3[n2];
    const float b3v  = b3[0];

    const float4 g4  = ((const float4*)lng)[tid & 31];
    const float4 bb4 = ((const float4*)lnb)[tid & 31];

    for (int t = 0; t < 4; ++t) {
        const int row0 = (blockIdx.x * 4 + t) * 64;

        // ---- Phase A: load 64x128 fp32 tile (fully contiguous), LayerNorm, bf16 -> LDS ----
        const float4* Xg = (const float4*)X + (size_t)row0 * 32;
#pragma unroll
        for (int i = 0; i < 8; ++i) {
            float4 v = Xg[tid + 256 * i];
            float s  = v.x + v.y + v.z + v.w;
            float s2 = v.x * v.x + v.y * v.y + v.z * v.z + v.w * v.w;
#pragma unroll
            for (int m = 1; m < 32; m <<= 1) {
                s  += __shfl_xor(s, m);
                s2 += __shfl_xor(s2, m);
            }
            const float mu  = s * 0.0078125f;
            const float var = s2 * 0.0078125f - mu * mu;
            const float rs  = rsqrtf(var + 1e-5f);
            const int row   = (tid + 256 * i) >> 5;
            const float y0 = (v.x - mu) * rs * g4.x + bb4.x;
            const float y1 = (v.y - mu) * rs * g4.y + bb4.y;
            const float y2 = (v.z - mu) * rs * g4.z + bb4.z;
            const float y3 = (v.w - mu) * rs * g4.w + bb4.w;
            uint2 pk;
            pk.x = (unsigned)f2bf(y0) | ((unsigned)f2bf(y1) << 16);
            pk.y = (unsigned)f2bf(y2) | ((unsigned)f2bf(y3) << 16);
            *reinterpret_cast<uint2*>(&Xl[row * PITCH + (tid & 31) * 4]) = pk;
        }
        __syncthreads();

        // ---- GEMM1: [64x128] @ [128x128] ----
        floatx4 acc[4][2];
#pragma unroll
        for (int rt = 0; rt < 4; ++rt)
#pragma unroll
            for (int c = 0; c < 2; ++c)
                acc[rt][c] = floatx4{0.f, 0.f, 0.f, 0.f};

#pragma unroll
        for (int kt = 0; kt < 4; ++kt) {
            ushortx8 a[4];
#pragma unroll
            for (int rt = 0; rt < 4; ++rt)
                a[rt] = *reinterpret_cast<const ushortx8*>(
                    &Xl[(rt * 16 + c16) * PITCH + kt * 32 + q * 8]);
#pragma unroll
            for (int rt = 0; rt < 4; ++rt) {
                acc[rt][0] = mfma16(a[rt], B1f[0][kt], acc[rt][0]);
                acc[rt][1] = mfma16(a[rt], B1f[1][kt], acc[rt][1]);
            }
        }

        // GELU + store H1 (bf16) to LDS. C layout: col=lane&15, row=q*4+r.
#pragma unroll
        for (int rt = 0; rt < 4; ++rt) {
#pragma unroll
            for (int c = 0; c < 2; ++c) {
                const float bb = c ? b1v1 : b1v0;
                const int col  = (2 * wave + c) * 16 + c16;
#pragma unroll
                for (int r = 0; r < 4; ++r) {
                    const float h = gelu_exact(acc[rt][c][r] + bb);
                    H1l[(rt * 16 + q * 4 + r) * PITCH + col] = f2bf(h);
                }
            }
        }
        __syncthreads();

        // ---- GEMM2: [64x128] @ [128x64] ----
        floatx4 acc2[4];
#pragma unroll
        for (int rt = 0; rt < 4; ++rt) acc2[rt] = floatx4{0.f, 0.f, 0.f, 0.f};
#pragma unroll
        for (int kt = 0; kt < 4; ++kt) {
            ushortx8 a[4];
#pragma unroll
            for (int rt = 0; rt < 4; ++rt)
                a[rt] = *reinterpret_cast<const ushortx8*>(
                    &H1l[(rt * 16 + c16) * PITCH + kt * 32 + q * 8]);
#pragma unroll
            for (int rt = 0; rt < 4; ++rt)
                acc2[rt] = mfma16(a[rt], B2f[kt], acc2[rt]);
        }

        // ---- Epilogue: gelu, *W3, reduce 16 cols per wave, combine across waves ----
#pragma unroll
        for (int rt = 0; rt < 4; ++rt) {
            floatx4 pv;
#pragma unroll
            for (int r = 0; r < 4; ++r)
                pv[r] = gelu_exact(acc2[rt][r] + b2v) * w3v;
#pragma unroll
            for (int m = 1; m < 16; m <<= 1) {
#pragma unroll
                for (int r = 0; r < 4; ++r) pv[r] += __shfl_xor(pv[r], m);
            }
            if (c16 == 0)
                *reinterpret_cast<floatx4*>(&part[wave * 64 + rt * 16 + q * 4]) = pv;
        }
        __syncthreads();

        // ---- Scatter scores via edge_index ----
        if (tid < 64) {
            const float sc = b3v + part[tid] + part[64 + tid] + part[128 + tid] + part[192 + tid];
            const int e  = row0 + tid;
            const int s  = ei[e];
            const int d  = ei[TOT + e];
            const int g  = s >> 6;            // N = 64
            const int ls = s & 63, ld = d & 63;
            const int i2 = min(ls, ld), j2 = max(ls, ld);
            if (ls != ld) {
                const int idx = i2 * Npn - ((i2 * (i2 + 1)) >> 1) + (j2 - i2 - 1);
                out[g * Eg + idx] = sc;
            }
        }
        __syncthreads();
    }
}

// Kernel 2: in-place softmax over each graph's 2016 logits. One block per graph.
__global__ __launch_bounds__(256)
void softmax_kernel(float* __restrict__ buf)
{
    __shared__ float red[4];
    const int tid  = threadIdx.x;
    const int wave = tid >> 6;
    const int lane = tid & 63;
    const int base = blockIdx.x * Eg;

    float v[8];
    float mx = -3.4e38f;
#pragma unroll
    for (int k = 0; k < 8; ++k) {
        const int idx = tid + 256 * k;
        v[k] = (idx < Eg) ? buf[base + idx] : -3.4e38f;
        mx = fmaxf(mx, v[k]);
    }
#pragma unroll
    for (int m = 1; m < 64; m <<= 1) mx = fmaxf(mx, __shfl_xor(mx, m));
    if (lane == 0) red[wave] = mx;
    __syncthreads();
    mx = fmaxf(fmaxf(red[0], red[1]), fmaxf(red[2], red[3]));
    __syncthreads();

    float sum = 0.f;
#pragma unroll
    for (int k = 0; k < 8; ++k) {
        const int idx = tid + 256 * k;
        if (idx < Eg) {
            v[k] = expf(v[k] - mx);
            sum += v[k];
        }
    }
#pragma unroll
    for (int m = 1; m < 64; m <<= 1) sum += __shfl_xor(sum, m);
    if (lane == 0) red[wave] = sum;
    __syncthreads();
    sum = red[0] + red[1] + red[2] + red[3];
    const float inv = 1.0f / sum;

#pragma unroll
    for (int k = 0; k < 8; ++k) {
        const int idx = tid + 256 * k;
        if (idx < Eg) buf[base + idx] = v[k] * inv;
    }
}

extern "C" void kernel_launch(void* const* d_in, const int* in_sizes, int n_in,
                              void* d_out, int out_size, void* d_ws, size_t ws_size,
                              hipStream_t stream)
{
    const float* Xf  = (const float*)d_in[0];   // edge_features [TOT,128]
    const int*   ei  = (const int*)d_in[1];     // edge_index [2, TOT]
    // d_in[2] batch, d_in[3] num_nodes_per_graph: unused (structure is canonical)
    const float* lng = (const float*)d_in[4];
    const float* lnb = (const float*)d_in[5];
    const float* W1  = (const float*)d_in[6];
    const float* b1  = (const float*)d_in[7];
    const float* W2  = (const float*)d_in[8];
    const float* b2  = (const float*)d_in[9];
    const float* W3  = (const float*)d_in[10];
    const float* b3  = (const float*)d_in[11];
    float* out = (float*)d_out;

    hipLaunchKernelGGL(scores_kernel, dim3(TOT / 256), dim3(256), 0, stream,
                       Xf, ei, lng, lnb, W1, b1, W2, b2, W3, b3, out);
    hipLaunchKernelGGL(softmax_kernel, dim3(Gg), dim3(256), 0, stream, out);
}